// Round 1
// baseline (352.084 us; speedup 1.0000x reference)
//
#include <hip/hip_runtime.h>
#include <hip/hip_bf16.h>

typedef short s16;
typedef __attribute__((ext_vector_type(8))) short bf16x8;  // 8 bf16 = 4 VGPR (MFMA A/B frag)
typedef __attribute__((ext_vector_type(4))) float f32x4;   // MFMA C/D frag

// ---------------- helpers ----------------
__device__ __forceinline__ s16 f2bf(float f) {
  // round-to-nearest-even fp32 -> bf16 (bits)
  unsigned u = __builtin_bit_cast(unsigned, f);
  unsigned r = (u + 0x7FFFu + ((u >> 16) & 1u)) >> 16;
  return (s16)r;
}

__device__ __forceinline__ float hsig(float x) {
  return fminf(fmaxf(0.2f * x + 0.5f, 0.0f), 1.0f);
}

// ---------------- prep kernels ----------------
// fp32 -> bf16 bulk convert (vectorized, n4 = n/4)
__global__ void cvt_kernel(const float* __restrict__ src, s16* __restrict__ dst, int n4) {
  int i = blockIdx.x * blockDim.x + threadIdx.x;
  int stride = gridDim.x * blockDim.x;
  for (; i < n4; i += stride) {
    float4 v = reinterpret_cast<const float4*>(src)[i];
    short4 o;
    o.x = f2bf(v.x); o.y = f2bf(v.y); o.z = f2bf(v.z); o.w = f2bf(v.w);
    reinterpret_cast<short4*>(dst)[i] = o;
  }
}

// rk [3,3,64,256] fp32 (HWIO) -> wt [9][256][64] bf16 ([tap][oc][ic], ic contiguous)
__global__ void wtrans_kernel(const float* __restrict__ rk, s16* __restrict__ wt) {
  int idx = blockIdx.x * blockDim.x + threadIdx.x;
  if (idx >= 9 * 256 * 64) return;
  int ic = idx & 63;
  int oc = (idx >> 6) & 255;
  int tap = idx >> 14;
  wt[idx] = f2bf(rk[(tap * 64 + ic) * 256 + oc]);
}

// k0 [3,3,1,256] fp32 -> k0t [256][32] bf16 (taps 0..8 in k slots 0..8, rest zero)
__global__ void k0trans_kernel(const float* __restrict__ k0, s16* __restrict__ wt) {
  int idx = blockIdx.x * blockDim.x + threadIdx.x;
  if (idx >= 256 * 32) return;
  int kk = idx & 31;
  int oc = idx >> 5;
  wt[idx] = (kk < 9) ? f2bf(k0[kk * 256 + oc]) : (s16)0;
}

// ---------------- ConvLSTM cell kernel ----------------
// Block: 512 threads = 8 waves. Tile: M=128 pixels (2 image rows), N=256 (all gates).
// Wave (mh = wave>>2, g = wave&3): 64 pixels x oc in {j*64 + g*16 .. +16} for j=0..3
// => gate j for feature f = g*16 + (lane&15): all 4 gates of (pixel,f) lane-local.
// grid: 1024 blocks: b = blk>>5, y0 = (blk&31)*2.
template <int NSRC, bool XPATH>
__global__ __launch_bounds__(512) void cell_kernel(
    const s16* __restrict__ src0,   // [B,64,64,64] bf16 (conv input 0)
    const s16* __restrict__ src1,   // [B,64,64,64] bf16 (conv input 1, NSRC==2)
    const s16* __restrict__ w0,     // [9][256][64] bf16
    const s16* __restrict__ w1,     // [9][256][64] bf16 (NSRC==2)
    const float* __restrict__ xin,  // [B,64,64] fp32 (XPATH)
    const s16* __restrict__ k0t,    // [256][32] bf16 (XPATH)
    const float* __restrict__ bias, // [256]
    const float* __restrict__ c_old,// [B,64,64,64] fp32
    float* __restrict__ h_out,
    float* __restrict__ c_out,
    s16* __restrict__ hb_out)       // bf16 copy of h (nullable)
{
  __shared__ __align__(16) s16 a_lds[NSRC * 4 * 64 * 64]; // [src][row 0..3][px 0..63][ic 0..63], swizzled
  __shared__ float x_lds[XPATH ? 4 * 64 : 1];

  const int tid = threadIdx.x;
  const int b  = blockIdx.x >> 5;
  const int y0 = (blockIdx.x & 31) << 1;

  // ---- stage input tiles (rows y0-1 .. y0+2, zero-padded), swizzle: cb ^= (px&7) ----
  for (int s = 0; s < NSRC; ++s) {
    const s16* src = (s == 0) ? src0 : src1;
    #pragma unroll
    for (int i = 0; i < 4; ++i) {
      int c   = tid + i * 512;        // 0..2047 16B-chunks
      int row = c >> 9;               // 0..3
      int px  = (c >> 3) & 63;
      int cb  = c & 7;                // channel block (8 bf16)
      int y   = y0 - 1 + row;
      bf16x8 val = {};
      if ((unsigned)y < 64u)
        val = *reinterpret_cast<const bf16x8*>(src + (((b * 64 + y) * 64 + px) * 64 + cb * 8));
      int dst = s * 16384 + (row * 64 + px) * 64 + ((cb ^ (px & 7)) * 8);
      *reinterpret_cast<bf16x8*>(a_lds + dst) = val;
    }
  }
  if (XPATH) {
    if (tid < 256) {
      int row = tid >> 6, px = tid & 63;
      int y = y0 - 1 + row;
      x_lds[tid] = ((unsigned)y < 64u) ? xin[(b * 64 + y) * 64 + px] : 0.0f;
    }
  }
  __syncthreads();

  const int wave = tid >> 6;
  const int lane = tid & 63;
  const int g    = wave & 3;   // oc sub-group
  const int mh   = wave >> 2;  // m half (0/1)
  const int l15  = lane & 15;
  const int l4   = lane >> 4;  // 0..3

  f32x4 acc[4][4] = {};  // [m-frag][gate j]

  // ---- x-conv as one zero-padded K=32 MFMA step (layer 0 only) ----
  if (XPATH) {
    bf16x8 bx[4];
    #pragma unroll
    for (int j = 0; j < 4; ++j) {
      int oc = j * 64 + g * 16 + l15;
      bx[j] = *reinterpret_cast<const bf16x8*>(k0t + oc * 32 + l4 * 8);
    }
    #pragma unroll
    for (int m = 0; m < 4; ++m) {
      int pl  = mh * 64 + m * 16 + l15;
      int row = pl >> 6, px = pl & 63;
      bf16x8 ax = {};
      #pragma unroll
      for (int j = 0; j < 8; ++j) {
        int t = l4 * 8 + j;          // tap index in k-slot
        if (t < 9) {
          int dy = t / 3, dx = t - dy * 3;
          int xx = px + dx - 1;
          float xv = ((unsigned)xx < 64u) ? x_lds[(row + dy) * 64 + xx] : 0.0f;
          ax[j] = f2bf(xv);
        }
      }
      #pragma unroll
      for (int j = 0; j < 4; ++j)
        acc[m][j] = __builtin_amdgcn_mfma_f32_16x16x32_bf16(ax, bx[j], acc[m][j], 0, 0, 0);
    }
  }

  // ---- main K loop: NSRC sources x 9 taps x (2 ksteps of 32 ic) ----
  for (int s = 0; s < NSRC; ++s) {
    const s16* wsrc  = (s == 0) ? w0 : w1;
    const s16* lbase = a_lds + s * 16384;
    int dy = 0, dx = 0;
    for (int tap = 0; tap < 9; ++tap) {
      const s16* wt = wsrc + tap * 16384;
      bf16x8 bfr[4][2];
      #pragma unroll
      for (int j = 0; j < 4; ++j) {
        int oc = j * 64 + g * 16 + l15;
        #pragma unroll
        for (int k = 0; k < 2; ++k)
          bfr[j][k] = *reinterpret_cast<const bf16x8*>(wt + oc * 64 + k * 32 + l4 * 8);
      }
      #pragma unroll
      for (int k = 0; k < 2; ++k) {
        #pragma unroll
        for (int m = 0; m < 4; ++m) {
          int pl   = mh * 64 + m * 16 + l15;
          int row  = (pl >> 6) + dy;          // 0..3 in tile
          int xx   = (pl & 63) + dx - 1;
          bool valid = (unsigned)xx < 64u;
          int xc   = valid ? xx : 0;
          int cb   = (k * 4 + l4) ^ (xc & 7); // swizzled channel block
          bf16x8 a = *reinterpret_cast<const bf16x8*>(lbase + (row * 64 + xc) * 64 + cb * 8);
          if (!valid) a = (bf16x8){};
          #pragma unroll
          for (int j = 0; j < 4; ++j)
            acc[m][j] = __builtin_amdgcn_mfma_f32_16x16x32_bf16(a, bfr[j][k], acc[m][j], 0, 0, 0);
        }
      }
      if (++dx == 3) { dx = 0; ++dy; }
    }
  }

  // ---- LSTM epilogue (lane-local: all 4 gates of (p,f) in same lane/reg) ----
  float bi[4];
  #pragma unroll
  for (int j = 0; j < 4; ++j) bi[j] = bias[j * 64 + g * 16 + l15];

  const int pix_base = b * 4096 + y0 * 64;
  const int f = g * 16 + l15;
  #pragma unroll
  for (int m = 0; m < 4; ++m) {
    #pragma unroll
    for (int r = 0; r < 4; ++r) {
      int pl = mh * 64 + m * 16 + l4 * 4 + r;  // D row = (lane>>4)*4 + r
      int off = (pix_base + pl) * 64 + f;
      float zi = acc[m][0][r] + bi[0];
      float zf = acc[m][1][r] + bi[1];
      float zc = acc[m][2][r] + bi[2];
      float zo = acc[m][3][r] + bi[3];
      float ig = hsig(zi), fg = hsig(zf), og = hsig(zo);
      float cn = fg * c_old[off] + ig * tanhf(zc);
      float hn = og * tanhf(cn);
      c_out[off] = cn;
      h_out[off] = hn;
      if (hb_out) hb_out[off] = f2bf(hn);
    }
  }
}

// ---------------- 1x1 conv head ----------------
// frames[p] = sum_f h1n[p,f]*cw[f] + cb ; 4 lanes per pixel, 16 ch each
__global__ void frames_kernel(const float* __restrict__ h, const float* __restrict__ cw,
                              const float* __restrict__ cbp, float* __restrict__ out) {
  int tid = blockIdx.x * 256 + threadIdx.x;
  int p  = tid >> 2;
  int fc = (tid & 3) * 16;
  const float4* hp = reinterpret_cast<const float4*>(h + p * 64 + fc);
  const float4* wp = reinterpret_cast<const float4*>(cw + fc);
  float s = 0.0f;
  #pragma unroll
  for (int i = 0; i < 4; ++i) {
    float4 v = hp[i];
    float4 w = wp[i];
    s += v.x * w.x + v.y * w.y + v.z * w.z + v.w * w.w;
  }
  s += __shfl_xor(s, 1);
  s += __shfl_xor(s, 2);
  if ((tid & 3) == 0) out[p] = s + cbp[0];
}

// ---------------- launch ----------------
extern "C" void kernel_launch(void* const* d_in, const int* in_sizes, int n_in,
                              void* d_out, int out_size, void* d_ws, size_t ws_size,
                              hipStream_t stream) {
  const float* x   = (const float*)d_in[0];
  const float* h0  = (const float*)d_in[1];
  const float* c0  = (const float*)d_in[2];
  const float* h1  = (const float*)d_in[3];
  const float* c1  = (const float*)d_in[4];
  const float* k0  = (const float*)d_in[5];
  const float* rk0 = (const float*)d_in[6];
  const float* b0  = (const float*)d_in[7];
  const float* k1  = (const float*)d_in[8];
  const float* rk1 = (const float*)d_in[9];
  const float* b1  = (const float*)d_in[10];
  const float* cw  = (const float*)d_in[11];
  const float* cbp = (const float*)d_in[12];

  float* out    = (float*)d_out;
  float* frames = out;                       // [32,64,64,1]
  float* h0n    = out + 131072;              // [32,64,64,64]
  float* c0n    = out + 131072 + 8388608;
  float* h1n    = out + 131072 + 2 * 8388608;
  float* c1n    = out + 131072 + 3 * 8388608;

  char* ws = (char*)d_ws;
  const size_t SZ_H = 16777216;  // bytes per bf16 [32,64,64,64] buffer
  s16* h0b  = (s16*)(ws + 0 * SZ_H);
  s16* h1b  = (s16*)(ws + 1 * SZ_H);
  s16* h0nb = (s16*)(ws + 2 * SZ_H);
  s16* w0t  = (s16*)(ws + 3 * SZ_H);                 // rk0^T
  s16* w1t  = (s16*)(ws + 3 * SZ_H + 1 * 294912);    // k1^T
  s16* w2t  = (s16*)(ws + 3 * SZ_H + 2 * 294912);    // rk1^T
  s16* k0t  = (s16*)(ws + 3 * SZ_H + 3 * 294912);    // k0 padded [256][32]

  // prep
  cvt_kernel<<<2048, 256, 0, stream>>>(h0, h0b, 2097152);
  cvt_kernel<<<2048, 256, 0, stream>>>(h1, h1b, 2097152);
  wtrans_kernel<<<576, 256, 0, stream>>>(rk0, w0t);
  wtrans_kernel<<<576, 256, 0, stream>>>(k1, w1t);
  wtrans_kernel<<<576, 256, 0, stream>>>(rk1, w2t);
  k0trans_kernel<<<32, 256, 0, stream>>>(k0, k0t);

  // layer 0: z = conv(x,k0) + conv(h0,rk0) + b0
  cell_kernel<1, true><<<1024, 512, 0, stream>>>(
      h0b, nullptr, w0t, nullptr, x, k0t, b0, c0, h0n, c0n, h0nb);

  // layer 1: z = conv(h0n,k1) + conv(h1,rk1) + b1
  cell_kernel<2, false><<<1024, 512, 0, stream>>>(
      h0nb, h1b, w1t, w2t, nullptr, nullptr, b1, c1, h1n, c1n, nullptr);

  // head
  frames_kernel<<<2048, 256, 0, stream>>>(h1n, cw, cbp, frames);
}

// Round 2
// 314.157 us; speedup vs baseline: 1.1207x; 1.1207x over previous
//
#include <hip/hip_runtime.h>
#include <hip/hip_bf16.h>

typedef short s16;
typedef __attribute__((ext_vector_type(8))) short bf16x8;  // 8 bf16 = 4 VGPR (MFMA A/B frag)
typedef __attribute__((ext_vector_type(4))) float f32x4;   // MFMA C/D frag

// ---------------- helpers ----------------
__device__ __forceinline__ s16 f2bf(float f) {
  // round-to-nearest-even fp32 -> bf16 (bits)
  unsigned u = __builtin_bit_cast(unsigned, f);
  unsigned r = (u + 0x7FFFu + ((u >> 16) & 1u)) >> 16;
  return (s16)r;
}

__device__ __forceinline__ float hsig(float x) {
  return fminf(fmaxf(0.2f * x + 0.5f, 0.0f), 1.0f);
}

// ---------------- prep kernels ----------------
// fp32 -> bf16 bulk convert (vectorized, n4 = n/4)
__global__ void cvt_kernel(const float* __restrict__ src, s16* __restrict__ dst, int n4) {
  int i = blockIdx.x * blockDim.x + threadIdx.x;
  int stride = gridDim.x * blockDim.x;
  for (; i < n4; i += stride) {
    float4 v = reinterpret_cast<const float4*>(src)[i];
    short4 o;
    o.x = f2bf(v.x); o.y = f2bf(v.y); o.z = f2bf(v.z); o.w = f2bf(v.w);
    reinterpret_cast<short4*>(dst)[i] = o;
  }
}

// rk [3,3,64,256] fp32 (HWIO) -> wt [9][256][64] bf16 ([tap][oc][ic], ic contiguous)
__global__ void wtrans_kernel(const float* __restrict__ rk, s16* __restrict__ wt) {
  int idx = blockIdx.x * blockDim.x + threadIdx.x;
  if (idx >= 9 * 256 * 64) return;
  int ic = idx & 63;
  int oc = (idx >> 6) & 255;
  int tap = idx >> 14;
  wt[idx] = f2bf(rk[(tap * 64 + ic) * 256 + oc]);
}

// k0 [3,3,1,256] fp32 -> k0t [256][32] bf16 (taps 0..8 in k slots 0..8, rest zero)
__global__ void k0trans_kernel(const float* __restrict__ k0, s16* __restrict__ wt) {
  int idx = blockIdx.x * blockDim.x + threadIdx.x;
  if (idx >= 256 * 32) return;
  int kk = idx & 31;
  int oc = idx >> 5;
  wt[idx] = (kk < 9) ? f2bf(k0[kk * 256 + oc]) : (s16)0;
}

// ---------------- ConvLSTM cell kernel ----------------
// Block: 512 threads = 8 waves. Tile: M=128 pixels (2 image rows), N=256 (all gates).
// Wave (mh = wave>>2, g = wave&3): 64 pixels x oc in {j*64 + g*16 .. +16} for j=0..3
// => gate j for feature f = g*16 + (lane&15): all 4 gates of (pixel,f) lane-local.
// LDS A tile padded in x: stride 66 (xp = px+1; xp 0 and 65 zeroed) -> no boundary
// masking in the inner loop. Weight fragments double-buffered at half-tap (k-step)
// granularity so L2 latency hides under the previous stage's 16 MFMAs.
// grid: 1024 blocks: b = blk>>5, y0 = (blk&31)*2.
#define PXS 66                       // padded x stride (elements of 64-ch rows)
#define ROWSZ (PXS * 64)             // 4224 elements per tile row
#define SRCSZ (4 * ROWSZ)            // 16896 elements per source tile
template <int NSRC, bool XPATH>
__global__ __launch_bounds__(512, 4) void cell_kernel(
    const s16* __restrict__ src0,   // [B,64,64,64] bf16 (conv input 0)
    const s16* __restrict__ src1,   // [B,64,64,64] bf16 (conv input 1, NSRC==2)
    const s16* __restrict__ w0,     // [9][256][64] bf16
    const s16* __restrict__ w1,     // [9][256][64] bf16 (NSRC==2)
    const float* __restrict__ xin,  // [B,64,64] fp32 (XPATH)
    const s16* __restrict__ k0t,    // [256][32] bf16 (XPATH)
    const float* __restrict__ bias, // [256]
    const float* __restrict__ c_old,// [B,64,64,64] fp32
    float* __restrict__ h_out,
    float* __restrict__ c_out,
    s16* __restrict__ hb_out)       // bf16 copy of h (nullable)
{
  __shared__ __align__(16) s16 a_lds[NSRC * SRCSZ]; // [src][row 0..3][xp 0..65][ic 0..63], swizzled
  __shared__ float x_lds[XPATH ? 4 * 64 : 1];

  const int tid = threadIdx.x;
  const int b  = blockIdx.x >> 5;
  const int y0 = (blockIdx.x & 31) << 1;

  // ---- stage input tiles (rows y0-1 .. y0+2, zero-padded), swizzle: cb ^= (xp&7) ----
  #pragma unroll
  for (int s = 0; s < NSRC; ++s) {
    const s16* src = (s == 0) ? src0 : src1;
    #pragma unroll
    for (int i = 0; i < 4; ++i) {
      int c   = tid + i * 512;        // 0..2047 16B-chunks
      int row = c >> 9;               // 0..3
      int px  = (c >> 3) & 63;
      int cb  = c & 7;                // channel block (8 bf16)
      int y   = y0 - 1 + row;
      bf16x8 val = {};
      if ((unsigned)y < 64u)
        val = *reinterpret_cast<const bf16x8*>(src + (((b * 64 + y) * 64 + px) * 64 + cb * 8));
      int xp  = px + 1;
      int dst = s * SRCSZ + (row * PXS + xp) * 64 + ((cb ^ (xp & 7)) * 8);
      *reinterpret_cast<bf16x8*>(a_lds + dst) = val;
    }
  }
  // zero the x-border columns (xp = 0 and xp = 65)
  if (tid < NSRC * 64) {
    int s   = tid >> 6;
    int idx = tid & 63;
    int row = idx >> 4;
    int xp  = ((idx >> 3) & 1) ? 65 : 0;
    int cb  = idx & 7;
    bf16x8 z = {};
    *reinterpret_cast<bf16x8*>(a_lds + s * SRCSZ + (row * PXS + xp) * 64 + cb * 8) = z;
  }
  if (XPATH) {
    if (tid < 256) {
      int row = tid >> 6, px = tid & 63;
      int y = y0 - 1 + row;
      x_lds[tid] = ((unsigned)y < 64u) ? xin[(b * 64 + y) * 64 + px] : 0.0f;
    }
  }
  __syncthreads();

  const int wave = tid >> 6;
  const int lane = tid & 63;
  const int g    = wave & 3;   // oc sub-group
  const int mh   = wave >> 2;  // m half (0/1)
  const int l15  = lane & 15;
  const int l4   = lane >> 4;  // 0..3

  f32x4 acc[4][4] = {};  // [m-frag][gate j]

  // ---- x-conv as one zero-padded K=32 MFMA step (layer 0 only) ----
  if (XPATH) {
    bf16x8 bx[4];
    #pragma unroll
    for (int j = 0; j < 4; ++j) {
      int oc = j * 64 + g * 16 + l15;
      bx[j] = *reinterpret_cast<const bf16x8*>(k0t + oc * 32 + l4 * 8);
    }
    #pragma unroll
    for (int m = 0; m < 4; ++m) {
      int px  = m * 16 + l15;
      bf16x8 ax = {};
      #pragma unroll
      for (int j = 0; j < 8; ++j) {
        int t = l4 * 8 + j;          // tap index in k-slot
        if (t < 9) {
          int dy = t / 3, dx = t - dy * 3;
          int xx = px + dx - 1;
          float xv = ((unsigned)xx < 64u) ? x_lds[(mh + dy) * 64 + xx] : 0.0f;
          ax[j] = f2bf(xv);
        }
      }
      #pragma unroll
      for (int j = 0; j < 4; ++j)
        acc[m][j] = __builtin_amdgcn_mfma_f32_16x16x32_bf16(ax, bx[j], acc[m][j], 0, 0, 0);
    }
  }

  // ---- main K loop: 2T half-tap stages, weight double-buffer (prefetch depth 1) ----
  constexpr int T = NSRC * 9;
  const int woff = (g * 16 + l15) * 64 + l4 * 8;   // weight element offset (j adds 4096, k adds 32)
  const char* lbw = reinterpret_cast<const char*>(a_lds) + mh * (ROWSZ * 2); // wave's base row (bytes)

  bf16x8 wb[2][4];
  {
    const s16* wt = w0 + woff;  // stage 0: t=0,k=0
    #pragma unroll
    for (int j = 0; j < 4; ++j)
      wb[0][j] = *reinterpret_cast<const bf16x8*>(wt + j * 4096);
  }

  #pragma unroll
  for (int u = 0; u < 2 * T; ++u) {
    // prefetch stage u+1 weights (4 fragments)
    if (u + 1 < 2 * T) {
      int t2 = (u + 1) >> 1, k2 = (u + 1) & 1;
      const s16* wt = ((NSRC == 2 && t2 >= 9) ? w1 + (t2 - 9) * 16384
                                              : w0 + t2 * 16384) + k2 * 32 + woff;
      #pragma unroll
      for (int j = 0; j < 4; ++j)
        wb[(u + 1) & 1][j] = *reinterpret_cast<const bf16x8*>(wt + j * 4096);
    }
    // compute stage u
    {
      int t = u >> 1, k = u & 1;
      int tap = (NSRC == 2 && t >= 9) ? t - 9 : t;
      int dy = tap / 3, dx = tap - dy * 3;
      const char* lb = lbw + ((NSRC == 2 && t >= 9) ? SRCSZ * 2 : 0) + dy * (ROWSZ * 2);
      #pragma unroll
      for (int m = 0; m < 4; ++m) {
        int xq   = m * 16 + l15 + dx;           // padded x index (orig x = px+dx-1, +1 pad)
        int boff = xq * 128 + (((k << 6) | (l4 << 4)) ^ ((xq & 7) << 4));
        bf16x8 a = *reinterpret_cast<const bf16x8*>(lb + boff);
        #pragma unroll
        for (int j = 0; j < 4; ++j)
          acc[m][j] = __builtin_amdgcn_mfma_f32_16x16x32_bf16(a, wb[u & 1][j], acc[m][j], 0, 0, 0);
      }
    }
  }

  // ---- LSTM epilogue (lane-local: all 4 gates of (p,f) in same lane/reg) ----
  float bi[4];
  #pragma unroll
  for (int j = 0; j < 4; ++j) bi[j] = bias[j * 64 + g * 16 + l15];

  const int pix_base = b * 4096 + y0 * 64;
  const int f = g * 16 + l15;
  #pragma unroll
  for (int m = 0; m < 4; ++m) {
    #pragma unroll
    for (int r = 0; r < 4; ++r) {
      int pl = mh * 64 + m * 16 + l4 * 4 + r;  // D row = (lane>>4)*4 + r
      int off = (pix_base + pl) * 64 + f;
      float zi = acc[m][0][r] + bi[0];
      float zf = acc[m][1][r] + bi[1];
      float zc = acc[m][2][r] + bi[2];
      float zo = acc[m][3][r] + bi[3];
      float ig = hsig(zi), fg = hsig(zf), og = hsig(zo);
      float cn = fg * c_old[off] + ig * tanhf(zc);
      float hn = og * tanhf(cn);
      c_out[off] = cn;
      h_out[off] = hn;
      if (hb_out) hb_out[off] = f2bf(hn);
    }
  }
}

// ---------------- 1x1 conv head ----------------
// frames[p] = sum_f h1n[p,f]*cw[f] + cb ; 4 lanes per pixel, 16 ch each
__global__ void frames_kernel(const float* __restrict__ h, const float* __restrict__ cw,
                              const float* __restrict__ cbp, float* __restrict__ out) {
  int tid = blockIdx.x * 256 + threadIdx.x;
  int p  = tid >> 2;
  int fc = (tid & 3) * 16;
  const float4* hp = reinterpret_cast<const float4*>(h + p * 64 + fc);
  const float4* wp = reinterpret_cast<const float4*>(cw + fc);
  float s = 0.0f;
  #pragma unroll
  for (int i = 0; i < 4; ++i) {
    float4 v = hp[i];
    float4 w = wp[i];
    s += v.x * w.x + v.y * w.y + v.z * w.z + v.w * w.w;
  }
  s += __shfl_xor(s, 1);
  s += __shfl_xor(s, 2);
  if ((tid & 3) == 0) out[p] = s + cbp[0];
}

// ---------------- launch ----------------
extern "C" void kernel_launch(void* const* d_in, const int* in_sizes, int n_in,
                              void* d_out, int out_size, void* d_ws, size_t ws_size,
                              hipStream_t stream) {
  const float* x   = (const float*)d_in[0];
  const float* h0  = (const float*)d_in[1];
  const float* c0  = (const float*)d_in[2];
  const float* h1  = (const float*)d_in[3];
  const float* c1  = (const float*)d_in[4];
  const float* k0  = (const float*)d_in[5];
  const float* rk0 = (const float*)d_in[6];
  const float* b0  = (const float*)d_in[7];
  const float* k1  = (const float*)d_in[8];
  const float* rk1 = (const float*)d_in[9];
  const float* b1  = (const float*)d_in[10];
  const float* cw  = (const float*)d_in[11];
  const float* cbp = (const float*)d_in[12];

  float* out    = (float*)d_out;
  float* frames = out;                       // [32,64,64,1]
  float* h0n    = out + 131072;              // [32,64,64,64]
  float* c0n    = out + 131072 + 8388608;
  float* h1n    = out + 131072 + 2 * 8388608;
  float* c1n    = out + 131072 + 3 * 8388608;

  char* ws = (char*)d_ws;
  const size_t SZ_H = 16777216;  // bytes per bf16 [32,64,64,64] buffer
  s16* h0b  = (s16*)(ws + 0 * SZ_H);
  s16* h1b  = (s16*)(ws + 1 * SZ_H);
  s16* h0nb = (s16*)(ws + 2 * SZ_H);
  s16* w0t  = (s16*)(ws + 3 * SZ_H);                 // rk0^T
  s16* w1t  = (s16*)(ws + 3 * SZ_H + 1 * 294912);    // k1^T
  s16* w2t  = (s16*)(ws + 3 * SZ_H + 2 * 294912);    // rk1^T
  s16* k0t  = (s16*)(ws + 3 * SZ_H + 3 * 294912);    // k0 padded [256][32]

  // prep
  cvt_kernel<<<2048, 256, 0, stream>>>(h0, h0b, 2097152);
  cvt_kernel<<<2048, 256, 0, stream>>>(h1, h1b, 2097152);
  wtrans_kernel<<<576, 256, 0, stream>>>(rk0, w0t);
  wtrans_kernel<<<576, 256, 0, stream>>>(k1, w1t);
  wtrans_kernel<<<576, 256, 0, stream>>>(rk1, w2t);
  k0trans_kernel<<<32, 256, 0, stream>>>(k0, k0t);

  // layer 0: z = conv(x,k0) + conv(h0,rk0) + b0
  cell_kernel<1, true><<<1024, 512, 0, stream>>>(
      h0b, nullptr, w0t, nullptr, x, k0t, b0, c0, h0n, c0n, h0nb);

  // layer 1: z = conv(h0n,k1) + conv(h1,rk1) + b1
  cell_kernel<2, false><<<1024, 512, 0, stream>>>(
      h0nb, h1b, w1t, w2t, nullptr, nullptr, b1, c1, h1n, c1n, nullptr);

  // head
  frames_kernel<<<2048, 256, 0, stream>>>(h1n, cw, cbp, frames);
}

// Round 3
// 219.458 us; speedup vs baseline: 1.6043x; 1.4315x over previous
//
#include <hip/hip_runtime.h>
#include <hip/hip_bf16.h>

typedef short s16;
typedef __attribute__((ext_vector_type(8))) short bf16x8;  // 8 bf16 = 4 VGPR (MFMA A/B frag)
typedef __attribute__((ext_vector_type(4))) float f32x4;   // MFMA C/D frag

// ---------------- helpers ----------------
__device__ __forceinline__ s16 f2bf(float f) {
  unsigned u = __builtin_bit_cast(unsigned, f);
  unsigned r = (u + 0x7FFFu + ((u >> 16) & 1u)) >> 16;
  return (s16)r;
}

__device__ __forceinline__ float hsig(float x) {
  return fminf(fmaxf(0.2f * x + 0.5f, 0.0f), 1.0f);
}

// ---------------- prep kernels ----------------
__global__ void cvt_kernel(const float* __restrict__ src, s16* __restrict__ dst, int n4) {
  int i = blockIdx.x * blockDim.x + threadIdx.x;
  int stride = gridDim.x * blockDim.x;
  for (; i < n4; i += stride) {
    float4 v = reinterpret_cast<const float4*>(src)[i];
    short4 o;
    o.x = f2bf(v.x); o.y = f2bf(v.y); o.z = f2bf(v.z); o.w = f2bf(v.w);
    reinterpret_cast<short4*>(dst)[i] = o;
  }
}

// rk [3,3,64,256] fp32 (HWIO) -> wt [9][256][64] bf16 ([tap][oc][ic])
__global__ void wtrans_kernel(const float* __restrict__ rk, s16* __restrict__ wt) {
  int idx = blockIdx.x * blockDim.x + threadIdx.x;
  if (idx >= 9 * 256 * 64) return;
  int ic = idx & 63;
  int oc = (idx >> 6) & 255;
  int tap = idx >> 14;
  wt[idx] = f2bf(rk[(tap * 64 + ic) * 256 + oc]);
}

// k0 [3,3,1,256] fp32 -> k0t [256][32] bf16 (taps 0..8 in k slots 0..8, rest zero)
__global__ void k0trans_kernel(const float* __restrict__ k0, s16* __restrict__ wt) {
  int idx = blockIdx.x * blockDim.x + threadIdx.x;
  if (idx >= 256 * 32) return;
  int kk = idx & 31;
  int oc = idx >> 5;
  wt[idx] = (kk < 9) ? f2bf(k0[kk * 256 + oc]) : (s16)0;
}

// ---------------- ConvLSTM cell kernel ----------------
// Block: 1024 threads = 16 waves. Tile: M=256 pixels (4 image rows), N=256 (all gates).
// Wave (mh = wave>>2 in 0..3, g = wave&3): output row y0+mh (64 px), oc set
// {j*64 + g*16 + 0..15} for j=0..3 -> all 4 gates of (pixel, f) lane-local.
// A tile: 6 rows (y0-1..y0+4) x padded stride 66, XOR-swizzled, staged once.
// Weights: per half-tap stage, the 16 KB slice [256 oc][32 ic] is staged to LDS
// via global_load_lds (1 x 16B per thread), double-buffered, counted vmcnt(1) +
// raw s_barrier (no __syncthreads in loop -> loads stay in flight across barriers).
// LDS W layout [icg 0..3][oc 0..255][8] == linear thread order (t*16 B).
// grid: 512 blocks: b = blk>>4, y0 = (blk&15)*4.
#define PXS 66
#define ROWSZ (PXS * 64)             // 4224 elements per tile row
#define SRCSZ (6 * ROWSZ)            // 25344 elements per source tile
template <int NSRC, bool XPATH>
__global__ __launch_bounds__(1024, 4) void cell_kernel(
    const s16* __restrict__ src0,   // [B,64,64,64] bf16
    const s16* __restrict__ src1,   // [B,64,64,64] bf16 (NSRC==2)
    const s16* __restrict__ w0,     // [9][256][64] bf16
    const s16* __restrict__ w1,     // [9][256][64] bf16 (NSRC==2)
    const float* __restrict__ xin,  // [B,64,64] fp32 (XPATH)
    const s16* __restrict__ k0t,    // [256][32] bf16 (XPATH)
    const float* __restrict__ bias, // [256]
    const float* __restrict__ c_old,// [B,64,64,64] fp32
    float* __restrict__ h_out,
    float* __restrict__ c_out,
    s16* __restrict__ hb_out)       // bf16 copy of h (nullable)
{
  __shared__ __align__(16) s16 a_lds[NSRC * SRCSZ];
  __shared__ __align__(16) s16 w_lds[2][8192];   // 2 x 16 KB
  __shared__ float x_lds[XPATH ? 384 : 1];

  const int tid = threadIdx.x;
  const int b  = blockIdx.x >> 4;
  const int y0 = (blockIdx.x & 15) << 2;

  // ---- stage A tiles (rows y0-1 .. y0+4, zero-padded), swizzle: cb ^= (xp&7) ----
  for (int s = 0; s < NSRC; ++s) {
    const s16* src = (s == 0) ? src0 : src1;
    #pragma unroll
    for (int i = 0; i < 3; ++i) {
      int c   = tid + i * 1024;       // 0..3071 16B-chunks
      int row = c >> 9;               // 0..5
      int px  = (c >> 3) & 63;
      int cb  = c & 7;
      int y   = y0 - 1 + row;
      bf16x8 val = {};
      if ((unsigned)y < 64u)
        val = *reinterpret_cast<const bf16x8*>(src + (((b * 64 + y) * 64 + px) * 64 + cb * 8));
      int xp  = px + 1;
      *reinterpret_cast<bf16x8*>(a_lds + s * SRCSZ + (row * PXS + xp) * 64 + ((cb ^ (xp & 7)) * 8)) = val;
    }
  }
  // zero x-border columns (xp = 0, 65)
  if (tid < NSRC * 96) {
    int s   = tid / 96;
    int r   = tid % 96;
    int row = r >> 4;
    int xp  = ((r >> 3) & 1) ? 65 : 0;
    int cb  = r & 7;
    bf16x8 z = {};
    *reinterpret_cast<bf16x8*>(a_lds + s * SRCSZ + (row * PXS + xp) * 64 + cb * 8) = z;
  }
  if (XPATH) {
    if (tid < 384) {
      int row = tid >> 6, px = tid & 63;
      int y = y0 - 1 + row;
      x_lds[tid] = ((unsigned)y < 64u) ? xin[(b * 64 + y) * 64 + px] : 0.0f;
    }
  }
  __syncthreads();

  const int wave = tid >> 6;
  const int lane = tid & 63;
  const int g    = wave & 3;
  const int mh   = wave >> 2;   // output row within the 4-row tile
  const int l15  = lane & 15;
  const int l4   = lane >> 4;

  f32x4 acc[4][4] = {};  // [m-frag][gate j]

  // ---- weight stage issue (1 x 16B global_load_lds per thread) ----
  const int w_goff = (tid & 255) * 64 + (tid >> 8) * 8;  // oc*64 + icg*8
  char* wl0 = (char*)(&w_lds[0][0]) + ((tid >> 6) << 10); // wave-uniform base (wave*1024 B)
  auto issueW = [&](int u) {
    int t2 = u >> 1, k = u & 1;
    int si  = (NSRC == 2 && t2 >= 9) ? 1 : 0;
    int tap = t2 - 9 * si;
    const s16* wt = (si ? w1 : w0) + tap * 16384 + k * 32 + w_goff;
    char* dst = wl0 + ((u & 1) ? 16384 : 0);
    __builtin_amdgcn_global_load_lds((const __attribute__((address_space(1))) void*)wt,
                                     (__attribute__((address_space(3))) void*)dst, 16, 0, 0);
  };

  // ---- x-conv as one zero-padded K=32 MFMA step (layer 0 only) ----
  if (XPATH) {
    bf16x8 bx[4];
    #pragma unroll
    for (int j = 0; j < 4; ++j) {
      int oc = j * 64 + g * 16 + l15;
      bx[j] = *reinterpret_cast<const bf16x8*>(k0t + oc * 32 + l4 * 8);
    }
    #pragma unroll
    for (int m = 0; m < 4; ++m) {
      int px = m * 16 + l15;
      bf16x8 ax = {};
      #pragma unroll
      for (int j = 0; j < 8; ++j) {
        int t = l4 * 8 + j;
        if (t < 9) {
          int dy = t / 3, dx = t - dy * 3;
          int xx = px + dx - 1;
          float xv = ((unsigned)xx < 64u) ? x_lds[(mh + dy) * 64 + xx] : 0.0f;
          ax[j] = f2bf(xv);
        }
      }
      #pragma unroll
      for (int j = 0; j < 4; ++j)
        acc[m][j] = __builtin_amdgcn_mfma_f32_16x16x32_bf16(ax, bx[j], acc[m][j], 0, 0, 0);
    }
  }

  // ---- main K loop: NST half-tap stages, W in LDS double-buffer ----
  constexpr int NST = NSRC * 18;
  issueW(0);
  #pragma unroll
  for (int u = 0; u < NST; ++u) {
    issueW((u + 1 == NST) ? 0 : u + 1);        // wrap dummy keeps vmcnt uniform
    asm volatile("s_waitcnt vmcnt(1)" ::: "memory");  // own stage-u load landed
    __builtin_amdgcn_s_barrier();              // all waves' stage-u loads landed
    __builtin_amdgcn_sched_barrier(0);

    const char* wb = (const char*)(&w_lds[u & 1][0]);
    bf16x8 wf[4];
    #pragma unroll
    for (int j = 0; j < 4; ++j) {
      int oc = j * 64 + g * 16 + l15;
      wf[j] = *reinterpret_cast<const bf16x8*>(wb + l4 * 4096 + oc * 16);
    }
    int t2 = u >> 1, k = u & 1;
    int si  = (NSRC == 2 && t2 >= 9) ? 1 : 0;
    int tap = t2 - 9 * si;
    int dy = tap / 3, dx = tap - dy * 3;
    const char* lb = (const char*)a_lds + si * (SRCSZ * 2) + (mh + dy) * (ROWSZ * 2);
    #pragma unroll
    for (int m = 0; m < 4; ++m) {
      int xq   = m * 16 + l15 + dx;
      int boff = xq * 128 + (((k << 6) | (l4 << 4)) ^ ((xq & 7) << 4));
      bf16x8 a = *reinterpret_cast<const bf16x8*>(lb + boff);
      #pragma unroll
      for (int j = 0; j < 4; ++j)
        acc[m][j] = __builtin_amdgcn_mfma_f32_16x16x32_bf16(a, wf[j], acc[m][j], 0, 0, 0);
    }
    __builtin_amdgcn_sched_barrier(0);
    __builtin_amdgcn_s_barrier();              // reads of buf[u&1] done before overwrite
  }

  // ---- LSTM epilogue (lane-local gates) ----
  float bi[4];
  #pragma unroll
  for (int j = 0; j < 4; ++j) bi[j] = bias[j * 64 + g * 16 + l15];

  const int pix_base = b * 4096 + y0 * 64;
  const int f = g * 16 + l15;
  #pragma unroll
  for (int m = 0; m < 4; ++m) {
    #pragma unroll
    for (int r = 0; r < 4; ++r) {
      int pl = mh * 64 + m * 16 + l4 * 4 + r;
      int off = (pix_base + pl) * 64 + f;
      float zi = acc[m][0][r] + bi[0];
      float zf = acc[m][1][r] + bi[1];
      float zc = acc[m][2][r] + bi[2];
      float zo = acc[m][3][r] + bi[3];
      float ig = hsig(zi), fg = hsig(zf), og = hsig(zo);
      float cn = fg * c_old[off] + ig * tanhf(zc);
      float hn = og * tanhf(cn);
      c_out[off] = cn;
      h_out[off] = hn;
      if (hb_out) hb_out[off] = f2bf(hn);
    }
  }
}

// ---------------- 1x1 conv head ----------------
__global__ void frames_kernel(const float* __restrict__ h, const float* __restrict__ cw,
                              const float* __restrict__ cbp, float* __restrict__ out) {
  int tid = blockIdx.x * 256 + threadIdx.x;
  int p  = tid >> 2;
  int fc = (tid & 3) * 16;
  const float4* hp = reinterpret_cast<const float4*>(h + p * 64 + fc);
  const float4* wp = reinterpret_cast<const float4*>(cw + fc);
  float s = 0.0f;
  #pragma unroll
  for (int i = 0; i < 4; ++i) {
    float4 v = hp[i];
    float4 w = wp[i];
    s += v.x * w.x + v.y * w.y + v.z * w.z + v.w * w.w;
  }
  s += __shfl_xor(s, 1);
  s += __shfl_xor(s, 2);
  if ((tid & 3) == 0) out[p] = s + cbp[0];
}

// ---------------- launch ----------------
extern "C" void kernel_launch(void* const* d_in, const int* in_sizes, int n_in,
                              void* d_out, int out_size, void* d_ws, size_t ws_size,
                              hipStream_t stream) {
  const float* x   = (const float*)d_in[0];
  const float* h0  = (const float*)d_in[1];
  const float* c0  = (const float*)d_in[2];
  const float* h1  = (const float*)d_in[3];
  const float* c1  = (const float*)d_in[4];
  const float* k0  = (const float*)d_in[5];
  const float* rk0 = (const float*)d_in[6];
  const float* b0  = (const float*)d_in[7];
  const float* k1  = (const float*)d_in[8];
  const float* rk1 = (const float*)d_in[9];
  const float* b1  = (const float*)d_in[10];
  const float* cw  = (const float*)d_in[11];
  const float* cbp = (const float*)d_in[12];

  float* out    = (float*)d_out;
  float* frames = out;                       // [32,64,64,1]
  float* h0n    = out + 131072;              // [32,64,64,64]
  float* c0n    = out + 131072 + 8388608;
  float* h1n    = out + 131072 + 2 * 8388608;
  float* c1n    = out + 131072 + 3 * 8388608;

  char* ws = (char*)d_ws;
  const size_t SZ_H = 16777216;  // bytes per bf16 [32,64,64,64] buffer
  s16* h0b  = (s16*)(ws + 0 * SZ_H);
  s16* h1b  = (s16*)(ws + 1 * SZ_H);
  s16* h0nb = (s16*)(ws + 2 * SZ_H);
  s16* w0t  = (s16*)(ws + 3 * SZ_H);                 // rk0^T
  s16* w1t  = (s16*)(ws + 3 * SZ_H + 1 * 294912);    // k1^T
  s16* w2t  = (s16*)(ws + 3 * SZ_H + 2 * 294912);    // rk1^T
  s16* k0t  = (s16*)(ws + 3 * SZ_H + 3 * 294912);    // k0 padded [256][32]

  // prep
  cvt_kernel<<<2048, 256, 0, stream>>>(h0, h0b, 2097152);
  cvt_kernel<<<2048, 256, 0, stream>>>(h1, h1b, 2097152);
  wtrans_kernel<<<576, 256, 0, stream>>>(rk0, w0t);
  wtrans_kernel<<<576, 256, 0, stream>>>(k1, w1t);
  wtrans_kernel<<<576, 256, 0, stream>>>(rk1, w2t);
  k0trans_kernel<<<32, 256, 0, stream>>>(k0, k0t);

  // layer 0: z = conv(x,k0) + conv(h0,rk0) + b0
  cell_kernel<1, true><<<512, 1024, 0, stream>>>(
      h0b, nullptr, w0t, nullptr, x, k0t, b0, c0, h0n, c0n, h0nb);

  // layer 1: z = conv(h0n,k1) + conv(h1,rk1) + b1
  cell_kernel<2, false><<<512, 1024, 0, stream>>>(
      h0nb, h1b, w1t, w2t, nullptr, nullptr, b1, c1, h1n, c1n, nullptr);

  // head
  frames_kernel<<<2048, 256, 0, stream>>>(h1n, cw, cbp, frames);
}

// Round 4
// 208.977 us; speedup vs baseline: 1.6848x; 1.0502x over previous
//
#include <hip/hip_runtime.h>
#include <hip/hip_bf16.h>

typedef short s16;
typedef __attribute__((ext_vector_type(8))) short bf16x8;  // 8 bf16 = 4 VGPR (MFMA A/B frag)
typedef __attribute__((ext_vector_type(4))) float f32x4;   // MFMA C/D frag

// ---------------- helpers ----------------
__device__ __forceinline__ s16 f2bf(float f) {
  unsigned u = __builtin_bit_cast(unsigned, f);
  unsigned r = (u + 0x7FFFu + ((u >> 16) & 1u)) >> 16;
  return (s16)r;
}

__device__ __forceinline__ float hsig(float x) {
  return fminf(fmaxf(0.2f * x + 0.5f, 0.0f), 1.0f);
}

// ---------------- prep kernel (all weight transposes in one launch) ----------------
// w0t/w1t/w2t: [3,3,ic,256] fp32 -> [9][256][64] bf16 ; k0t: [3,3,1,256] -> [256][32]
__global__ void wprep_kernel(const float* __restrict__ rk0, const float* __restrict__ k1,
                             const float* __restrict__ rk1, const float* __restrict__ k0,
                             s16* __restrict__ w0t, s16* __restrict__ w1t,
                             s16* __restrict__ w2t, s16* __restrict__ k0t) {
  int idx = blockIdx.x * 256 + threadIdx.x;
  const int n1 = 9 * 256 * 64;  // 147456
  if (idx < 3 * n1) {
    int which = idx / n1;
    int r = idx - which * n1;
    int ic = r & 63;
    int oc = (r >> 6) & 255;
    int tap = r >> 14;
    const float* src = (which == 0) ? rk0 : (which == 1) ? k1 : rk1;
    s16* dst = (which == 0) ? w0t : (which == 1) ? w1t : w2t;
    dst[r] = f2bf(src[(tap * 64 + ic) * 256 + oc]);
  } else if (idx < 3 * n1 + 8192) {
    int r = idx - 3 * n1;
    int kk = r & 31;
    int oc = r >> 5;
    k0t[r] = (kk < 9) ? f2bf(k0[kk * 256 + oc]) : (s16)0;
  }
}

// ---------------- ConvLSTM cell kernel ----------------
// Block: 1024 threads = 16 waves. Tile: M=256 pixels (4 image rows), N=256 (all gates).
// Wave (mh = wave>>2, g = wave&3): output row y0+mh, oc {j*64+g*16+0..15}, j=0..3
// -> all 4 gates of (pixel, f) lane-local for the LSTM epilogue.
// A tile: 6 rows x padded stride 66, XOR-swizzled, staged once (fp32 srcs converted inline).
// W: per half-tap stage 16 KB slice, TRIPLE-buffered LDS via global_load_lds,
// W-fragments register-prefetched one stage ahead (wfA/wfB ping-pong), ONE
// vmcnt(0)+s_barrier per stage. NST % 3 == 0 keeps buffer slots consistent on wrap.
#define PXS 66
#define ROWSZ (PXS * 64)             // 4224 elements per tile row
#define SRCSZ (6 * ROWSZ)            // 25344 elements per source tile
template <bool F32>
__device__ __forceinline__ bf16x8 load_conv8(const void* src, long off) {
  if constexpr (F32) {
    const float* p = (const float*)src + off;
    float4 v0 = *reinterpret_cast<const float4*>(p);
    float4 v1 = *reinterpret_cast<const float4*>(p + 4);
    bf16x8 r;
    r[0] = f2bf(v0.x); r[1] = f2bf(v0.y); r[2] = f2bf(v0.z); r[3] = f2bf(v0.w);
    r[4] = f2bf(v1.x); r[5] = f2bf(v1.y); r[6] = f2bf(v1.z); r[7] = f2bf(v1.w);
    return r;
  } else {
    return *reinterpret_cast<const bf16x8*>((const s16*)src + off);
  }
}

template <int NSRC, bool XPATH, bool S0F32, bool S1F32>
__global__ __launch_bounds__(1024, 4) void cell_kernel(
    const void* __restrict__ src0,  // [B,64,64,64] bf16 or fp32
    const void* __restrict__ src1,  // [B,64,64,64] bf16 or fp32 (NSRC==2)
    const s16* __restrict__ w0,     // [9][256][64] bf16
    const s16* __restrict__ w1,     // [9][256][64] bf16 (NSRC==2)
    const float* __restrict__ xin,  // [B,64,64] fp32 (XPATH)
    const s16* __restrict__ k0t,    // [256][32] bf16 (XPATH)
    const float* __restrict__ bias, // [256]
    const float* __restrict__ c_old,// [B,64,64,64] fp32
    float* __restrict__ h_out,
    float* __restrict__ c_out,
    s16* __restrict__ hb_out)       // bf16 copy of h (nullable)
{
  __shared__ __align__(16) s16 a_lds[NSRC * SRCSZ];
  __shared__ __align__(16) s16 w_lds[3][8192];   // 3 x 16 KB
  __shared__ float x_lds[XPATH ? 384 : 1];

  const int tid = threadIdx.x;
  const int b  = blockIdx.x >> 4;
  const int y0 = (blockIdx.x & 15) << 2;

  // ---- stage A tiles (rows y0-1 .. y0+4, zero-padded), swizzle: cb ^= (xp&7) ----
  #pragma unroll
  for (int i = 0; i < 3; ++i) {
    int c   = tid + i * 1024;       // 0..3071 16B-chunks
    int row = c >> 9;               // 0..5
    int px  = (c >> 3) & 63;
    int cb  = c & 7;
    int y   = y0 - 1 + row;
    int xp  = px + 1;
    long goff = ((long)(b * 64 + y) * 64 + px) * 64 + cb * 8;
    int  doff = (row * PXS + xp) * 64 + ((cb ^ (xp & 7)) * 8);
    bf16x8 v0 = {};
    if ((unsigned)y < 64u) v0 = load_conv8<S0F32>(src0, goff);
    *reinterpret_cast<bf16x8*>(a_lds + doff) = v0;
    if (NSRC == 2) {
      bf16x8 v1 = {};
      if ((unsigned)y < 64u) v1 = load_conv8<S1F32>(src1, goff);
      *reinterpret_cast<bf16x8*>(a_lds + SRCSZ + doff) = v1;
    }
  }
  // zero x-border columns (xp = 0, 65)
  if (tid < NSRC * 96) {
    int s   = tid / 96;
    int r   = tid % 96;
    int row = r >> 4;
    int xp  = ((r >> 3) & 1) ? 65 : 0;
    int cb  = r & 7;
    bf16x8 z = {};
    *reinterpret_cast<bf16x8*>(a_lds + s * SRCSZ + (row * PXS + xp) * 64 + cb * 8) = z;
  }
  if (XPATH) {
    if (tid < 384) {
      int row = tid >> 6, px = tid & 63;
      int y = y0 - 1 + row;
      x_lds[tid] = ((unsigned)y < 64u) ? xin[(b * 64 + y) * 64 + px] : 0.0f;
    }
  }

  const int wave = tid >> 6;
  const int lane = tid & 63;
  const int g    = wave & 3;
  const int mh   = wave >> 2;
  const int l15  = lane & 15;
  const int l4   = lane >> 4;

  constexpr int NST = NSRC * 18;   // 18 or 36; both % 3 == 0
  const int w_goff = (tid & 255) * 64 + (tid >> 8) * 8;  // oc*64 + icg*8
  char* wl0 = (char*)(&w_lds[0][0]) + ((tid >> 6) << 10); // wave-uniform slice base
  auto issueW = [&](int u) {
    int uu = (u >= NST) ? u - NST : u;   // wrap dummy; slot uu%3 == u%3 since NST%3==0
    int t2 = uu >> 1, k = uu & 1;
    int si  = (NSRC == 2 && t2 >= 9) ? 1 : 0;
    int tap = t2 - 9 * si;
    const s16* wt = (si ? w1 : w0) + tap * 16384 + k * 32 + w_goff;
    char* dst = wl0 + (uu % 3) * 16384;
    __builtin_amdgcn_global_load_lds((const __attribute__((address_space(1))) void*)wt,
                                     (__attribute__((address_space(3))) void*)dst, 16, 0, 0);
  };

  issueW(0);
  issueW(1);
  __syncthreads();   // drains vmcnt+lgkm: staging visible AND W slots 0,1 valid

  f32x4 acc[4][4] = {};  // [m-frag][gate j]

  // ---- x-conv as one zero-padded K=32 MFMA step (layer 0 only) ----
  if (XPATH) {
    bf16x8 bx[4];
    #pragma unroll
    for (int j = 0; j < 4; ++j) {
      int oc = j * 64 + g * 16 + l15;
      bx[j] = *reinterpret_cast<const bf16x8*>(k0t + oc * 32 + l4 * 8);
    }
    #pragma unroll
    for (int m = 0; m < 4; ++m) {
      int px = m * 16 + l15;
      bf16x8 ax = {};
      #pragma unroll
      for (int j = 0; j < 8; ++j) {
        int t = l4 * 8 + j;
        if (t < 9) {
          int dy = t / 3, dx = t - dy * 3;
          int xx = px + dx - 1;
          float xv = ((unsigned)xx < 64u) ? x_lds[(mh + dy) * 64 + xx] : 0.0f;
          ax[j] = f2bf(xv);
        }
      }
      #pragma unroll
      for (int j = 0; j < 4; ++j)
        acc[m][j] = __builtin_amdgcn_mfma_f32_16x16x32_bf16(ax, bx[j], acc[m][j], 0, 0, 0);
    }
  }

  // ---- main K loop: W-frag register prefetch + 3-buf LDS, one barrier/stage ----
  const char* wbuf  = (const char*)(&w_lds[0][0]);
  const int   wroff = l4 * 4096;
  auto readW = [&](bf16x8* wf, int slot) {
    const char* wb = wbuf + slot * 16384 + wroff;
    #pragma unroll
    for (int j = 0; j < 4; ++j) {
      int oc = j * 64 + g * 16 + l15;
      wf[j] = *reinterpret_cast<const bf16x8*>(wb + oc * 16);
    }
  };
  auto doStage = [&](const bf16x8* wf, int u) {  // u compile-time via unroll
    int t2 = u >> 1, k = u & 1;
    int si  = (NSRC == 2 && t2 >= 9) ? 1 : 0;
    int tap = t2 - 9 * si;
    int dy = tap / 3, dx = tap - dy * 3;
    const char* lb = (const char*)a_lds + si * (SRCSZ * 2) + (mh + dy) * (ROWSZ * 2);
    #pragma unroll
    for (int m = 0; m < 4; ++m) {
      int xq   = m * 16 + l15 + dx;
      int boff = xq * 128 + (((k << 6) | (l4 << 4)) ^ ((xq & 7) << 4));
      bf16x8 a = *reinterpret_cast<const bf16x8*>(lb + boff);
      #pragma unroll
      for (int j = 0; j < 4; ++j)
        acc[m][j] = __builtin_amdgcn_mfma_f32_16x16x32_bf16(a, wf[j], acc[m][j], 0, 0, 0);
    }
  };

  bf16x8 wfA[4], wfB[4];
  readW(wfA, 0);
  #pragma unroll
  for (int u = 0; u < NST; u += 2) {
    issueW(u + 2);
    readW(wfB, (u + 1) % 3);
    doStage(wfA, u);
    asm volatile("s_waitcnt vmcnt(0)" ::: "memory");
    __builtin_amdgcn_s_barrier();
    issueW(u + 3);
    readW(wfA, (u + 2) % 3);
    doStage(wfB, u + 1);
    asm volatile("s_waitcnt vmcnt(0)" ::: "memory");
    __builtin_amdgcn_s_barrier();
  }

  // ---- LSTM epilogue (lane-local gates) ----
  float bi[4];
  #pragma unroll
  for (int j = 0; j < 4; ++j) bi[j] = bias[j * 64 + g * 16 + l15];

  const int pix_base = b * 4096 + y0 * 64;
  const int f = g * 16 + l15;
  #pragma unroll
  for (int m = 0; m < 4; ++m) {
    #pragma unroll
    for (int r = 0; r < 4; ++r) {
      int pl = mh * 64 + m * 16 + l4 * 4 + r;
      int off = (pix_base + pl) * 64 + f;
      float zi = acc[m][0][r] + bi[0];
      float zf = acc[m][1][r] + bi[1];
      float zc = acc[m][2][r] + bi[2];
      float zo = acc[m][3][r] + bi[3];
      float ig = hsig(zi), fg = hsig(zf), og = hsig(zo);
      float cn = fg * c_old[off] + ig * tanhf(zc);
      float hn = og * tanhf(cn);
      c_out[off] = cn;
      h_out[off] = hn;
      if (hb_out) hb_out[off] = f2bf(hn);
    }
  }
}

// ---------------- 1x1 conv head ----------------
__global__ void frames_kernel(const float* __restrict__ h, const float* __restrict__ cw,
                              const float* __restrict__ cbp, float* __restrict__ out) {
  int tid = blockIdx.x * 256 + threadIdx.x;
  int p  = tid >> 2;
  int fc = (tid & 3) * 16;
  const float4* hp = reinterpret_cast<const float4*>(h + p * 64 + fc);
  const float4* wp = reinterpret_cast<const float4*>(cw + fc);
  float s = 0.0f;
  #pragma unroll
  for (int i = 0; i < 4; ++i) {
    float4 v = hp[i];
    float4 w = wp[i];
    s += v.x * w.x + v.y * w.y + v.z * w.z + v.w * w.w;
  }
  s += __shfl_xor(s, 1);
  s += __shfl_xor(s, 2);
  if ((tid & 3) == 0) out[p] = s + cbp[0];
}

// ---------------- launch ----------------
extern "C" void kernel_launch(void* const* d_in, const int* in_sizes, int n_in,
                              void* d_out, int out_size, void* d_ws, size_t ws_size,
                              hipStream_t stream) {
  const float* x   = (const float*)d_in[0];
  const float* h0  = (const float*)d_in[1];
  const float* c0  = (const float*)d_in[2];
  const float* h1  = (const float*)d_in[3];
  const float* c1  = (const float*)d_in[4];
  const float* k0  = (const float*)d_in[5];
  const float* rk0 = (const float*)d_in[6];
  const float* b0  = (const float*)d_in[7];
  const float* k1  = (const float*)d_in[8];
  const float* rk1 = (const float*)d_in[9];
  const float* b1  = (const float*)d_in[10];
  const float* cw  = (const float*)d_in[11];
  const float* cbp = (const float*)d_in[12];

  float* out    = (float*)d_out;
  float* frames = out;                       // [32,64,64,1]
  float* h0n    = out + 131072;              // [32,64,64,64]
  float* c0n    = out + 131072 + 8388608;
  float* h1n    = out + 131072 + 2 * 8388608;
  float* c1n    = out + 131072 + 3 * 8388608;

  char* ws = (char*)d_ws;
  const size_t SZ_H = 16777216;  // bytes per bf16 [32,64,64,64] buffer
  s16* h0nb = (s16*)(ws + 0 * SZ_H);
  s16* w0t  = (s16*)(ws + 1 * SZ_H);                 // rk0^T
  s16* w1t  = (s16*)(ws + 1 * SZ_H + 1 * 294912);    // k1^T
  s16* w2t  = (s16*)(ws + 1 * SZ_H + 2 * 294912);    // rk1^T
  s16* k0t  = (s16*)(ws + 1 * SZ_H + 3 * 294912);    // k0 padded [256][32]

  // prep (single launch)
  wprep_kernel<<<1760, 256, 0, stream>>>(rk0, k1, rk1, k0, w0t, w1t, w2t, k0t);

  // layer 0: z = conv(x,k0) + conv(h0,rk0) + b0   (h0 converted inline)
  cell_kernel<1, true, true, false><<<512, 1024, 0, stream>>>(
      h0, nullptr, w0t, nullptr, x, k0t, b0, c0, h0n, c0n, h0nb);

  // layer 1: z = conv(h0n,k1) + conv(h1,rk1) + b1  (h1 converted inline)
  cell_kernel<2, false, false, true><<<512, 1024, 0, stream>>>(
      h0nb, h1, w1t, w2t, nullptr, nullptr, b1, c1, h1n, c1n, nullptr);

  // head
  frames_kernel<<<2048, 256, 0, stream>>>(h1n, cw, cbp, frames);
}